// Round 5
// baseline (990.260 us; speedup 1.0000x reference)
//
#include <hip/hip_runtime.h>

#define B_SZ 8192
#define IN_SZ 1024
#define G_SZ 100
#define F_SZ 128

using f32x4 = __attribute__((ext_vector_type(4))) float;
using s16x8 = __attribute__((ext_vector_type(8))) short;
typedef __bf16 bf16x8 __attribute__((ext_vector_type(8)));

__device__ __forceinline__ short cvt_bf16(float f) {      // HW RNE f32->bf16
    __bf16 h = (__bf16)f;
    return __builtin_bit_cast(short, h);
}
__device__ __forceinline__ float bfs2f(short s) {
    union { unsigned u; float f; } v; v.u = ((unsigned)(unsigned short)s) << 16;
    return v.f;
}

// ---------------------------------------------------------------------------
// Gather: Ag[g][b][f] = bf16(x[b][uf[g*128+f]]).
// ---------------------------------------------------------------------------
__global__ __launch_bounds__(256) void k_gather(const float* __restrict__ x,
                                                const int* __restrict__ uf,
                                                unsigned short* __restrict__ Ag) {
    __shared__ __align__(16) unsigned short xrow[16][1032];
    const int t = threadIdx.x;
    const int b0 = blockIdx.x * 16;
    #pragma unroll
    for (int i = 0; i < 16; ++i) {
        int c4 = t + i * 256;
        int r = c4 >> 8;
        int cc = (c4 & 255) << 2;
        float4 v = *reinterpret_cast<const float4*>(&x[(size_t)(b0 + r) * IN_SZ + cc]);
        ushort4 o;
        o.x = (unsigned short)cvt_bf16(v.x); o.y = (unsigned short)cvt_bf16(v.y);
        o.z = (unsigned short)cvt_bf16(v.z); o.w = (unsigned short)cvt_bf16(v.w);
        *reinterpret_cast<ushort4*>(&xrow[r][cc]) = o;
    }
    __syncthreads();
    for (int i = 0; i < 200; ++i) {
        int c = t + i * 256;
        int ch = c & 31; int r = (c >> 5) & 15; int g = c >> 9;
        int4 id = *reinterpret_cast<const int4*>(&uf[g * F_SZ + ch * 4]);
        ushort4 o;
        o.x = xrow[r][id.x]; o.y = xrow[r][id.y]; o.z = xrow[r][id.z]; o.w = xrow[r][id.w];
        *reinterpret_cast<ushort4*>(&Ag[(((size_t)g * B_SZ + b0 + r) << 7) + ch * 4]) = o;
    }
}

// ---------------------------------------------------------------------------
// Pre-pack W (+bias in k==K_SRC slot when FOLD) into MFMA fragment order:
//   P[g][(ks*NT+nt)*64 + lane] = 8 bf16 for (n = nt*16+(lane&15),
//                                            k = ks*32+(lane>>4)*8 .. +7)
// ---------------------------------------------------------------------------
template<int K_SRC, int N_OUT, int NT, bool FOLD>
__device__ __forceinline__ void pack_one(int e, const float* __restrict__ W,
                                         const float* __restrict__ bias,
                                         unsigned short* __restrict__ P) {
    constexpr int EPG = 4 * NT * 64;
    int g = e / EPG; int r = e - g * EPG;
    int lane = r & 63; int nt = (r >> 6) % NT; int ks = r / (64 * NT);
    int n = nt * 16 + (lane & 15); int kb = ks * 32 + (lane >> 4) * 8;
    s16x8 v;
    #pragma unroll
    for (int j = 0; j < 8; ++j) {
        int k = kb + j; float val = 0.f;
        if (n < N_OUT) {
            if (k < K_SRC) val = W[((size_t)g * K_SRC + k) * N_OUT + n];
            else if (FOLD && k == K_SRC) val = bias[g * N_OUT + n];
        }
        v[j] = cvt_bf16(val);
    }
    *reinterpret_cast<s16x8*>(&P[(size_t)e * 8]) = v;
}

__global__ __launch_bounds__(256) void k_packW(
    const float* __restrict__ w0,
    const float* __restrict__ w1, const float* __restrict__ b1,
    const float* __restrict__ w2, const float* __restrict__ b2,
    unsigned short* __restrict__ p0, unsigned short* __restrict__ p1,
    unsigned short* __restrict__ p2) {
    int id = blockIdx.x * 256 + threadIdx.x;           // 460800 total
    if (id < 179200)       pack_one<128, 100, 7, false>(id, w0, nullptr, p0);
    else if (id < 358400)  pack_one<100, 100, 7, true >(id - 179200, w1, b1, p1);
    else                   pack_one<100,  50, 4, true >(id - 358400, w2, b2, p2);
}

// ---------------------------------------------------------------------------
// Per-group dense, bf16 MFMA 16x16x32.  Main loop has NO LDS, NO BARRIERS:
//  - A fragments loaded directly from global (coalesced rows), BN+ReLU in reg.
//  - W fragments read per-lane from pre-packed table (L2-hot: 64 blocks/group
//    share a 28KB table).  Bias folded via k==K_SRC slot (FOLD).
//  - !IS_LAST: bf16 Hout store + BN stats: shfl -> LDS reduce -> ONE global
//    atomic per channel per block (direct global atomics were a 125MB write
//    amplification in R4).
//  - IS_LAST: swapped operands mfma(W,A) -> D[n][b]: float2 pred stores +
//    2-shfl out_weight dot.
// ---------------------------------------------------------------------------
template<int K_SRC, int N_OUT, int NT, bool BN_IN, bool IS_LAST, bool FOLD>
__global__ __launch_bounds__(256, 8) void k_dense(
    const unsigned short* __restrict__ Ain,   // [G][B][K_SRC] bf16
    const unsigned short* __restrict__ Wf,    // [G][EPG][8] packed
    const float* __restrict__ bias,           // only used when !FOLD
    const float* __restrict__ sa, const float* __restrict__ sb, // [G*K_SRC]
    unsigned short* __restrict__ Hout,        // [G][B][N_OUT] bf16
    float* __restrict__ pred,                 // [B][5000] f32
    float* __restrict__ ssum, float* __restrict__ ssq, // [G*N_OUT]
    const float* __restrict__ ow, float* __restrict__ out_acc)
{
    constexpr int EPG = 4 * NT * 64;
    __shared__ float ls1[NT * 16];
    __shared__ float ls2[NT * 16];
    const int t = threadIdx.x;
    const int g = blockIdx.x >> 6;
    const int m0 = (blockIdx.x & 63) << 7;
    const int lane = t & 63, wid = t >> 6;
    const int lr = lane & 15, lg = lane >> 4;

    const unsigned short* wbase = Wf + ((size_t)g * EPG + lane) * 8;
    const unsigned short* arow0 = Ain + ((size_t)g * B_SZ + m0 + wid * 32 + lr) * K_SRC;
    const unsigned short* arow1 = arow0 + (size_t)16 * K_SRC;

    f32x4 acc[2][NT] = {};
    constexpr int NKS_FULL = K_SRC / 32;

    #define APP(vv, idx, s, o) { float f_ = bfs2f(vv[idx]) * (s) + (o); \
                                 vv[idx] = cvt_bf16(fmaxf(f_, 0.f)); }

    #pragma unroll
    for (int ks = 0; ks < NKS_FULL; ++ks) {
        const int kb = ks * 32 + lg * 8;
        s16x8 a0, a1;
        if constexpr (K_SRC % 64 == 0) {
            a0 = *reinterpret_cast<const s16x8*>(arow0 + kb);
            a1 = *reinterpret_cast<const s16x8*>(arow1 + kb);
        } else {
            reinterpret_cast<short4*>(&a0)[0] = *reinterpret_cast<const short4*>(arow0 + kb);
            reinterpret_cast<short4*>(&a0)[1] = *reinterpret_cast<const short4*>(arow0 + kb + 4);
            reinterpret_cast<short4*>(&a1)[0] = *reinterpret_cast<const short4*>(arow1 + kb);
            reinterpret_cast<short4*>(&a1)[1] = *reinterpret_cast<const short4*>(arow1 + kb + 4);
        }
        if constexpr (BN_IN) {
            float4 S0 = *reinterpret_cast<const float4*>(&sa[g * K_SRC + kb]);
            float4 S1 = *reinterpret_cast<const float4*>(&sa[g * K_SRC + kb + 4]);
            float4 O0 = *reinterpret_cast<const float4*>(&sb[g * K_SRC + kb]);
            float4 O1 = *reinterpret_cast<const float4*>(&sb[g * K_SRC + kb + 4]);
            APP(a0,0,S0.x,O0.x) APP(a0,1,S0.y,O0.y) APP(a0,2,S0.z,O0.z) APP(a0,3,S0.w,O0.w)
            APP(a0,4,S1.x,O1.x) APP(a0,5,S1.y,O1.y) APP(a0,6,S1.z,O1.z) APP(a0,7,S1.w,O1.w)
            APP(a1,0,S0.x,O0.x) APP(a1,1,S0.y,O0.y) APP(a1,2,S0.z,O0.z) APP(a1,3,S0.w,O0.w)
            APP(a1,4,S1.x,O1.x) APP(a1,5,S1.y,O1.y) APP(a1,6,S1.z,O1.z) APP(a1,7,S1.w,O1.w)
        }
        bf16x8 av0 = __builtin_bit_cast(bf16x8, a0);
        bf16x8 av1 = __builtin_bit_cast(bf16x8, a1);
        #pragma unroll
        for (int nt = 0; nt < NT; ++nt) {
            s16x8 b = *reinterpret_cast<const s16x8*>(wbase + (size_t)((ks * NT + nt) * 64) * 8);
            bf16x8 bv = __builtin_bit_cast(bf16x8, b);
            if constexpr (IS_LAST) {
                acc[0][nt] = __builtin_amdgcn_mfma_f32_16x16x32_bf16(bv, av0, acc[0][nt], 0, 0, 0);
                acc[1][nt] = __builtin_amdgcn_mfma_f32_16x16x32_bf16(bv, av1, acc[1][nt], 0, 0, 0);
            } else {
                acc[0][nt] = __builtin_amdgcn_mfma_f32_16x16x32_bf16(av0, bv, acc[0][nt], 0, 0, 0);
                acc[1][nt] = __builtin_amdgcn_mfma_f32_16x16x32_bf16(av1, bv, acc[1][nt], 0, 0, 0);
            }
        }
    }

    if constexpr (K_SRC % 32 != 0) {          // tail: k = 96..99 (+bias slot)
        constexpr int kb0 = NKS_FULL * 32;
        s16x8 a0 = {}, a1 = {};
        if (lg == 0) {
            reinterpret_cast<short4*>(&a0)[0] = *reinterpret_cast<const short4*>(arow0 + kb0);
            reinterpret_cast<short4*>(&a1)[0] = *reinterpret_cast<const short4*>(arow1 + kb0);
            if constexpr (BN_IN) {
                float4 S0 = *reinterpret_cast<const float4*>(&sa[g * K_SRC + kb0]);
                float4 O0 = *reinterpret_cast<const float4*>(&sb[g * K_SRC + kb0]);
                APP(a0,0,S0.x,O0.x) APP(a0,1,S0.y,O0.y) APP(a0,2,S0.z,O0.z) APP(a0,3,S0.w,O0.w)
                APP(a1,0,S0.x,O0.x) APP(a1,1,S0.y,O0.y) APP(a1,2,S0.z,O0.z) APP(a1,3,S0.w,O0.w)
            }
            if constexpr (FOLD) { a0[4] = (short)0x3F80; a1[4] = (short)0x3F80; } // 1.0 -> bias row
        }
        bf16x8 av0 = __builtin_bit_cast(bf16x8, a0);
        bf16x8 av1 = __builtin_bit_cast(bf16x8, a1);
        #pragma unroll
        for (int nt = 0; nt < NT; ++nt) {
            s16x8 b = *reinterpret_cast<const s16x8*>(wbase + (size_t)((NKS_FULL * NT + nt) * 64) * 8);
            bf16x8 bv = __builtin_bit_cast(bf16x8, b);
            if constexpr (IS_LAST) {
                acc[0][nt] = __builtin_amdgcn_mfma_f32_16x16x32_bf16(bv, av0, acc[0][nt], 0, 0, 0);
                acc[1][nt] = __builtin_amdgcn_mfma_f32_16x16x32_bf16(bv, av1, acc[1][nt], 0, 0, 0);
            } else {
                acc[0][nt] = __builtin_amdgcn_mfma_f32_16x16x32_bf16(av0, bv, acc[0][nt], 0, 0, 0);
                acc[1][nt] = __builtin_amdgcn_mfma_f32_16x16x32_bf16(av1, bv, acc[1][nt], 0, 0, 0);
            }
        }
    }
    #undef APP

    // ---- epilogue ----
    if constexpr (!IS_LAST) {
        if (t < NT * 16) { ls1[t] = 0.f; ls2[t] = 0.f; }
        __syncthreads();
        #pragma unroll
        for (int nt = 0; nt < NT; ++nt) {
            const int col = nt * 16 + lr;
            const bool valid = col < N_OUT;
            float bv = 0.f;
            if constexpr (!FOLD) bv = valid ? bias[g * N_OUT + col] : 0.f;
            float s1 = 0.f, s2 = 0.f;
            #pragma unroll
            for (int mi = 0; mi < 2; ++mi) {
                const int rbase = m0 + wid * 32 + mi * 16 + (lg << 2);
                #pragma unroll
                for (int r = 0; r < 4; ++r) {
                    float v = acc[mi][nt][r] + bv;
                    short hb = cvt_bf16(v);
                    float vq = bfs2f(hb);
                    s1 += vq; s2 += vq * vq;
                    if (valid)
                        Hout[((size_t)g * B_SZ + rbase + r) * N_OUT + col] = (unsigned short)hb;
                }
            }
            s1 += __shfl_xor(s1, 16); s1 += __shfl_xor(s1, 32);
            s2 += __shfl_xor(s2, 16); s2 += __shfl_xor(s2, 32);
            if (valid && lg == 0) {
                atomicAdd(&ls1[col], s1);
                atomicAdd(&ls2[col], s2);
            }
        }
        __syncthreads();
        if (t < N_OUT) {
            atomicAdd(&ssum[g * N_OUT + t], ls1[t]);
            atomicAdd(&ssq[g * N_OUT + t], ls2[t]);
        }
    } else {
        // D[n][b]: n = nt*16 + lg*4 + r, b = m0 + wid*32 + mi*16 + lr
        #pragma unroll
        for (int mi = 0; mi < 2; ++mi) {
            const int b = m0 + wid * 32 + mi * 16 + lr;
            float dp = 0.f;
            #pragma unroll
            for (int nt = 0; nt < NT; ++nt) {
                const int n0 = nt * 16 + lg * 4;
                const size_t pb = (size_t)b * 5000 + g * N_OUT + n0;
                f32x4 v = acc[mi][nt];
                if (nt < 3) {
                    float2 w01 = *reinterpret_cast<const float2*>(&ow[g * N_OUT + n0]);
                    float2 w23 = *reinterpret_cast<const float2*>(&ow[g * N_OUT + n0 + 2]);
                    dp += v[0] * w01.x + v[1] * w01.y + v[2] * w23.x + v[3] * w23.y;
                    float2 o01; o01.x = v[0]; o01.y = v[1];
                    float2 o23; o23.x = v[2]; o23.y = v[3];
                    *reinterpret_cast<float2*>(&pred[pb]) = o01;
                    *reinterpret_cast<float2*>(&pred[pb + 2]) = o23;
                } else if (lg == 0) {            // n0 = 48: only n=48,49 valid
                    float2 w01 = *reinterpret_cast<const float2*>(&ow[g * N_OUT + n0]);
                    dp += v[0] * w01.x + v[1] * w01.y;
                    float2 o01; o01.x = v[0]; o01.y = v[1];
                    *reinterpret_cast<float2*>(&pred[pb]) = o01;
                }
            }
            dp += __shfl_xor(dp, 16); dp += __shfl_xor(dp, 32);
            if (lg == 0) atomicAdd(&out_acc[b], dp);
        }
    }
}

__global__ __launch_bounds__(256) void k_bnfin(const float* __restrict__ ssum,
                                               const float* __restrict__ ssq,
                                               const float* __restrict__ gamma,
                                               const float* __restrict__ beta,
                                               float* __restrict__ sa,
                                               float* __restrict__ sb, int n) {
    int c = blockIdx.x * 256 + threadIdx.x;
    if (c < n) {
        float mean = ssum[c] * (1.f / 8192.f);
        float var = ssq[c] * (1.f / 8192.f) - mean * mean;
        float s = rsqrtf(var + 1e-5f) * gamma[c];
        sa[c] = s;
        sb[c] = beta[c] - mean * s;
    }
}

__global__ __launch_bounds__(256) void k_sig(const float* __restrict__ out_acc,
                                             const float* __restrict__ ob,
                                             float* __restrict__ out) {
    int b = blockIdx.x * 256 + threadIdx.x;
    if (b < B_SZ) {
        float v = ob[0] + out_acc[b];
        out[b] = 1.f / (1.f + expf(-v));
    }
}

extern "C" void kernel_launch(void* const* d_in, const int* in_sizes, int n_in,
                              void* d_out, int out_size, void* d_ws, size_t ws_size,
                              hipStream_t stream) {
    const float* x      = (const float*)d_in[0];
    const int*   uf     = (const int*)d_in[1];
    const float* w0     = (const float*)d_in[2];
    const float* b0     = (const float*)d_in[3];
    const float* w1     = (const float*)d_in[4];
    const float* b1     = (const float*)d_in[5];
    const float* w2     = (const float*)d_in[6];
    const float* b2     = (const float*)d_in[7];
    const float* gamma0 = (const float*)d_in[8];
    const float* beta0  = (const float*)d_in[9];
    const float* gamma1 = (const float*)d_in[10];
    const float* beta1  = (const float*)d_in[11];
    const float* ow     = (const float*)d_in[12];
    const float* ob     = (const float*)d_in[13];

    char* ws = (char*)d_ws;
    const size_t AG_BYTES = (size_t)G_SZ * B_SZ * 128 * 2;  // 209,715,200
    unsigned short* Ag = (unsigned short*)ws;
    unsigned short* h1 = Ag;  // h1 aliases Ag (Ag dead after dense0)
    float* stat = (float*)(ws + AG_BYTES);
    float* sum0    = stat;            // 10000
    float* ssq0    = stat + 10000;
    float* sum1    = stat + 20000;
    float* ssq1    = stat + 30000;
    float* out_acc = stat + 40000;    // 8192
    float* sa0     = stat + 48192;
    float* sb0     = stat + 58192;
    float* sa1     = stat + 68192;
    float* sb1     = stat + 78192;    // stats end at 88192 floats (352,768 B)

    unsigned short* p0 = (unsigned short*)(ws + AG_BYTES + 88192 * 4);
    unsigned short* p1 = p0 + (size_t)179200 * 8;   // 2,867,200 B each
    unsigned short* p2 = p1 + (size_t)179200 * 8;   // p2: 1,638,400 B

    unsigned short* h0 = (unsigned short*)((float*)d_out + B_SZ);
    float* pred = (float*)d_out + B_SZ;
    float* sig  = (float*)d_out;

    hipMemsetAsync(stat, 0, 48192 * sizeof(float), stream);

    k_packW<<<1800, 256, 0, stream>>>(w0, w1, b1, w2, b2, p0, p1, p2);
    k_gather<<<B_SZ / 16, 256, 0, stream>>>(x, uf, Ag);

    k_dense<128, 100, 7, false, false, false><<<6400, 256, 0, stream>>>(
        Ag, p0, b0, nullptr, nullptr, h0, nullptr, sum0, ssq0, nullptr, nullptr);
    k_bnfin<<<40, 256, 0, stream>>>(sum0, ssq0, gamma0, beta0, sa0, sb0, 10000);

    k_dense<100, 100, 7, true, false, true><<<6400, 256, 0, stream>>>(
        h0, p1, nullptr, sa0, sb0, h1, nullptr, sum1, ssq1, nullptr, nullptr);
    k_bnfin<<<40, 256, 0, stream>>>(sum1, ssq1, gamma1, beta1, sa1, sb1, 10000);

    k_dense<100, 50, 4, true, true, true><<<6400, 256, 0, stream>>>(
        h1, p2, nullptr, sa1, sb1, nullptr, pred, nullptr, nullptr, ow, out_acc);

    k_sig<<<32, 256, 0, stream>>>(out_acc, ob, sig);
}

// Round 6
// 465.155 us; speedup vs baseline: 2.1289x; 2.1289x over previous
//
#include <hip/hip_runtime.h>

#define B_SZ 8192
#define IN_SZ 1024
#define G_SZ 100
#define F_SZ 128

using f32x4 = __attribute__((ext_vector_type(4))) float;
using s16x8 = __attribute__((ext_vector_type(8))) short;
typedef __bf16 bf16x8 __attribute__((ext_vector_type(8)));

__device__ __forceinline__ short cvt_bf16(float f) {      // HW RNE f32->bf16
    __bf16 h = (__bf16)f;
    return __builtin_bit_cast(short, h);
}
__device__ __forceinline__ float bfs2f(short s) {
    union { unsigned u; float f; } v; v.u = ((unsigned)(unsigned short)s) << 16;
    return v.f;
}

// ---------------------------------------------------------------------------
// Gather: Ag[g][b][f] = bf16(x[b][uf[g*128+f]]).
// ---------------------------------------------------------------------------
__global__ __launch_bounds__(256) void k_gather(const float* __restrict__ x,
                                                const int* __restrict__ uf,
                                                unsigned short* __restrict__ Ag) {
    __shared__ __align__(16) unsigned short xrow[16][1032];
    const int t = threadIdx.x;
    const int b0 = blockIdx.x * 16;
    #pragma unroll
    for (int i = 0; i < 16; ++i) {
        int c4 = t + i * 256;
        int r = c4 >> 8;
        int cc = (c4 & 255) << 2;
        float4 v = *reinterpret_cast<const float4*>(&x[(size_t)(b0 + r) * IN_SZ + cc]);
        ushort4 o;
        o.x = (unsigned short)cvt_bf16(v.x); o.y = (unsigned short)cvt_bf16(v.y);
        o.z = (unsigned short)cvt_bf16(v.z); o.w = (unsigned short)cvt_bf16(v.w);
        *reinterpret_cast<ushort4*>(&xrow[r][cc]) = o;
    }
    __syncthreads();
    for (int i = 0; i < 200; ++i) {
        int c = t + i * 256;
        int ch = c & 31; int r = (c >> 5) & 15; int g = c >> 9;
        int4 id = *reinterpret_cast<const int4*>(&uf[g * F_SZ + ch * 4]);
        ushort4 o;
        o.x = xrow[r][id.x]; o.y = xrow[r][id.y]; o.z = xrow[r][id.z]; o.w = xrow[r][id.w];
        *reinterpret_cast<ushort4*>(&Ag[(((size_t)g * B_SZ + b0 + r) << 7) + ch * 4]) = o;
    }
}

// ---------------------------------------------------------------------------
// Pre-pack W (+bias in k==K_SRC slot when FOLD) into MFMA fragment order:
//   P[g][(ks*NT+nt)*64 + lane] = 8 bf16 for (n = nt*16+(lane&15),
//                                            k = ks*32+(lane>>4)*8 .. +7)
// ---------------------------------------------------------------------------
template<int K_SRC, int N_OUT, int NT, bool FOLD>
__device__ __forceinline__ void pack_one(int e, const float* __restrict__ W,
                                         const float* __restrict__ bias,
                                         unsigned short* __restrict__ P) {
    constexpr int EPG = 4 * NT * 64;
    int g = e / EPG; int r = e - g * EPG;
    int lane = r & 63; int nt = (r >> 6) % NT; int ks = r / (64 * NT);
    int n = nt * 16 + (lane & 15); int kb = ks * 32 + (lane >> 4) * 8;
    s16x8 v;
    #pragma unroll
    for (int j = 0; j < 8; ++j) {
        int k = kb + j; float val = 0.f;
        if (n < N_OUT) {
            if (k < K_SRC) val = W[((size_t)g * K_SRC + k) * N_OUT + n];
            else if (FOLD && k == K_SRC) val = bias[g * N_OUT + n];
        }
        v[j] = cvt_bf16(val);
    }
    *reinterpret_cast<s16x8*>(&P[(size_t)e * 8]) = v;
}

__global__ __launch_bounds__(256) void k_packW(
    const float* __restrict__ w0,
    const float* __restrict__ w1, const float* __restrict__ b1,
    const float* __restrict__ w2, const float* __restrict__ b2,
    unsigned short* __restrict__ p0, unsigned short* __restrict__ p1,
    unsigned short* __restrict__ p2) {
    int id = blockIdx.x * 256 + threadIdx.x;           // 460800 total
    if (id < 179200)       pack_one<128, 100, 7, false>(id, w0, nullptr, p0);
    else if (id < 358400)  pack_one<100, 100, 7, true >(id - 179200, w1, b1, p1);
    else                   pack_one<100,  50, 4, true >(id - 358400, w2, b2, p2);
}

// ---------------------------------------------------------------------------
// Per-group dense, bf16 MFMA 16x16x32.  Main loop has NO LDS, NO BARRIERS:
//  - A fragments loaded directly from global (coalesced rows), BN+ReLU in reg.
//  - W fragments read per-lane from pre-packed table (L2-hot: 64 blocks/group
//    share a 28KB table).  Bias folded via k==K_SRC slot (FOLD).
//  - !IS_LAST: bf16 Hout store + BN stats: shfl -> LDS reduce -> ONE global
//    atomic per channel per block.
//  - IS_LAST: swapped operands mfma(W,A) -> D[n][b]: float2 pred stores +
//    2-shfl out_weight dot.
//  NOTE: launch_bounds must stay (256,4).  (256,8) caps VGPR at 64 -> the
//  56-VGPR accumulator spills to scratch -> 1.7GB/dispatch HBM (R5: 403us).
// ---------------------------------------------------------------------------
template<int K_SRC, int N_OUT, int NT, bool BN_IN, bool IS_LAST, bool FOLD>
__global__ __launch_bounds__(256, 4) void k_dense(
    const unsigned short* __restrict__ Ain,   // [G][B][K_SRC] bf16
    const unsigned short* __restrict__ Wf,    // [G][EPG][8] packed
    const float* __restrict__ bias,           // only used when !FOLD
    const float* __restrict__ sa, const float* __restrict__ sb, // [G*K_SRC]
    unsigned short* __restrict__ Hout,        // [G][B][N_OUT] bf16
    float* __restrict__ pred,                 // [B][5000] f32
    float* __restrict__ ssum, float* __restrict__ ssq, // [G*N_OUT]
    const float* __restrict__ ow, float* __restrict__ out_acc)
{
    constexpr int EPG = 4 * NT * 64;
    __shared__ float ls1[NT * 16];
    __shared__ float ls2[NT * 16];
    const int t = threadIdx.x;
    const int g = blockIdx.x >> 6;
    const int m0 = (blockIdx.x & 63) << 7;
    const int lane = t & 63, wid = t >> 6;
    const int lr = lane & 15, lg = lane >> 4;

    const unsigned short* wbase = Wf + ((size_t)g * EPG + lane) * 8;
    const unsigned short* arow0 = Ain + ((size_t)g * B_SZ + m0 + wid * 32 + lr) * K_SRC;
    const unsigned short* arow1 = arow0 + (size_t)16 * K_SRC;

    f32x4 acc[2][NT] = {};
    constexpr int NKS_FULL = K_SRC / 32;

    #define APP(vv, idx, s, o) { float f_ = bfs2f(vv[idx]) * (s) + (o); \
                                 vv[idx] = cvt_bf16(fmaxf(f_, 0.f)); }

    #pragma unroll
    for (int ks = 0; ks < NKS_FULL; ++ks) {
        const int kb = ks * 32 + lg * 8;
        s16x8 a0, a1;
        if constexpr (K_SRC % 64 == 0) {
            a0 = *reinterpret_cast<const s16x8*>(arow0 + kb);
            a1 = *reinterpret_cast<const s16x8*>(arow1 + kb);
        } else {
            reinterpret_cast<short4*>(&a0)[0] = *reinterpret_cast<const short4*>(arow0 + kb);
            reinterpret_cast<short4*>(&a0)[1] = *reinterpret_cast<const short4*>(arow0 + kb + 4);
            reinterpret_cast<short4*>(&a1)[0] = *reinterpret_cast<const short4*>(arow1 + kb);
            reinterpret_cast<short4*>(&a1)[1] = *reinterpret_cast<const short4*>(arow1 + kb + 4);
        }
        if constexpr (BN_IN) {
            float4 S0 = *reinterpret_cast<const float4*>(&sa[g * K_SRC + kb]);
            float4 S1 = *reinterpret_cast<const float4*>(&sa[g * K_SRC + kb + 4]);
            float4 O0 = *reinterpret_cast<const float4*>(&sb[g * K_SRC + kb]);
            float4 O1 = *reinterpret_cast<const float4*>(&sb[g * K_SRC + kb + 4]);
            APP(a0,0,S0.x,O0.x) APP(a0,1,S0.y,O0.y) APP(a0,2,S0.z,O0.z) APP(a0,3,S0.w,O0.w)
            APP(a0,4,S1.x,O1.x) APP(a0,5,S1.y,O1.y) APP(a0,6,S1.z,O1.z) APP(a0,7,S1.w,O1.w)
            APP(a1,0,S0.x,O0.x) APP(a1,1,S0.y,O0.y) APP(a1,2,S0.z,O0.z) APP(a1,3,S0.w,O0.w)
            APP(a1,4,S1.x,O1.x) APP(a1,5,S1.y,O1.y) APP(a1,6,S1.z,O1.z) APP(a1,7,S1.w,O1.w)
        }
        bf16x8 av0 = __builtin_bit_cast(bf16x8, a0);
        bf16x8 av1 = __builtin_bit_cast(bf16x8, a1);
        #pragma unroll
        for (int nt = 0; nt < NT; ++nt) {
            s16x8 b = *reinterpret_cast<const s16x8*>(wbase + (size_t)((ks * NT + nt) * 64) * 8);
            bf16x8 bv = __builtin_bit_cast(bf16x8, b);
            if constexpr (IS_LAST) {
                acc[0][nt] = __builtin_amdgcn_mfma_f32_16x16x32_bf16(bv, av0, acc[0][nt], 0, 0, 0);
                acc[1][nt] = __builtin_amdgcn_mfma_f32_16x16x32_bf16(bv, av1, acc[1][nt], 0, 0, 0);
            } else {
                acc[0][nt] = __builtin_amdgcn_mfma_f32_16x16x32_bf16(av0, bv, acc[0][nt], 0, 0, 0);
                acc[1][nt] = __builtin_amdgcn_mfma_f32_16x16x32_bf16(av1, bv, acc[1][nt], 0, 0, 0);
            }
        }
    }

    if constexpr (K_SRC % 32 != 0) {          // tail: k = 96..99 (+bias slot)
        constexpr int kb0 = NKS_FULL * 32;
        s16x8 a0 = {}, a1 = {};
        if (lg == 0) {
            reinterpret_cast<short4*>(&a0)[0] = *reinterpret_cast<const short4*>(arow0 + kb0);
            reinterpret_cast<short4*>(&a1)[0] = *reinterpret_cast<const short4*>(arow1 + kb0);
            if constexpr (BN_IN) {
                float4 S0 = *reinterpret_cast<const float4*>(&sa[g * K_SRC + kb0]);
                float4 O0 = *reinterpret_cast<const float4*>(&sb[g * K_SRC + kb0]);
                APP(a0,0,S0.x,O0.x) APP(a0,1,S0.y,O0.y) APP(a0,2,S0.z,O0.z) APP(a0,3,S0.w,O0.w)
                APP(a1,0,S0.x,O0.x) APP(a1,1,S0.y,O0.y) APP(a1,2,S0.z,O0.z) APP(a1,3,S0.w,O0.w)
            }
            if constexpr (FOLD) { a0[4] = (short)0x3F80; a1[4] = (short)0x3F80; } // 1.0 -> bias row
        }
        bf16x8 av0 = __builtin_bit_cast(bf16x8, a0);
        bf16x8 av1 = __builtin_bit_cast(bf16x8, a1);
        #pragma unroll
        for (int nt = 0; nt < NT; ++nt) {
            s16x8 b = *reinterpret_cast<const s16x8*>(wbase + (size_t)((NKS_FULL * NT + nt) * 64) * 8);
            bf16x8 bv = __builtin_bit_cast(bf16x8, b);
            if constexpr (IS_LAST) {
                acc[0][nt] = __builtin_amdgcn_mfma_f32_16x16x32_bf16(bv, av0, acc[0][nt], 0, 0, 0);
                acc[1][nt] = __builtin_amdgcn_mfma_f32_16x16x32_bf16(bv, av1, acc[1][nt], 0, 0, 0);
            } else {
                acc[0][nt] = __builtin_amdgcn_mfma_f32_16x16x32_bf16(av0, bv, acc[0][nt], 0, 0, 0);
                acc[1][nt] = __builtin_amdgcn_mfma_f32_16x16x32_bf16(av1, bv, acc[1][nt], 0, 0, 0);
            }
        }
    }
    #undef APP

    // ---- epilogue ----
    if constexpr (!IS_LAST) {
        if (t < NT * 16) { ls1[t] = 0.f; ls2[t] = 0.f; }
        __syncthreads();
        #pragma unroll
        for (int nt = 0; nt < NT; ++nt) {
            const int col = nt * 16 + lr;
            const bool valid = col < N_OUT;
            float bv = 0.f;
            if constexpr (!FOLD) bv = valid ? bias[g * N_OUT + col] : 0.f;
            float s1 = 0.f, s2 = 0.f;
            #pragma unroll
            for (int mi = 0; mi < 2; ++mi) {
                const int rbase = m0 + wid * 32 + mi * 16 + (lg << 2);
                #pragma unroll
                for (int r = 0; r < 4; ++r) {
                    float v = acc[mi][nt][r] + bv;
                    short hb = cvt_bf16(v);
                    float vq = bfs2f(hb);
                    s1 += vq; s2 += vq * vq;
                    if (valid)
                        Hout[((size_t)g * B_SZ + rbase + r) * N_OUT + col] = (unsigned short)hb;
                }
            }
            s1 += __shfl_xor(s1, 16); s1 += __shfl_xor(s1, 32);
            s2 += __shfl_xor(s2, 16); s2 += __shfl_xor(s2, 32);
            if (valid && lg == 0) {
                atomicAdd(&ls1[col], s1);
                atomicAdd(&ls2[col], s2);
            }
        }
        __syncthreads();
        if (t < N_OUT) {
            atomicAdd(&ssum[g * N_OUT + t], ls1[t]);
            atomicAdd(&ssq[g * N_OUT + t], ls2[t]);
        }
    } else {
        // D[n][b]: n = nt*16 + lg*4 + r, b = m0 + wid*32 + mi*16 + lr
        #pragma unroll
        for (int mi = 0; mi < 2; ++mi) {
            const int b = m0 + wid * 32 + mi * 16 + lr;
            float dp = 0.f;
            #pragma unroll
            for (int nt = 0; nt < NT; ++nt) {
                const int n0 = nt * 16 + lg * 4;
                const size_t pb = (size_t)b * 5000 + g * N_OUT + n0;
                f32x4 v = acc[mi][nt];
                if (nt < 3) {
                    float2 w01 = *reinterpret_cast<const float2*>(&ow[g * N_OUT + n0]);
                    float2 w23 = *reinterpret_cast<const float2*>(&ow[g * N_OUT + n0 + 2]);
                    dp += v[0] * w01.x + v[1] * w01.y + v[2] * w23.x + v[3] * w23.y;
                    float2 o01; o01.x = v[0]; o01.y = v[1];
                    float2 o23; o23.x = v[2]; o23.y = v[3];
                    *reinterpret_cast<float2*>(&pred[pb]) = o01;
                    *reinterpret_cast<float2*>(&pred[pb + 2]) = o23;
                } else if (lg == 0) {            // n0 = 48: only n=48,49 valid
                    float2 w01 = *reinterpret_cast<const float2*>(&ow[g * N_OUT + n0]);
                    dp += v[0] * w01.x + v[1] * w01.y;
                    float2 o01; o01.x = v[0]; o01.y = v[1];
                    *reinterpret_cast<float2*>(&pred[pb]) = o01;
                }
            }
            dp += __shfl_xor(dp, 16); dp += __shfl_xor(dp, 32);
            if (lg == 0) atomicAdd(&out_acc[b], dp);
        }
    }
}

__global__ __launch_bounds__(256) void k_bnfin(const float* __restrict__ ssum,
                                               const float* __restrict__ ssq,
                                               const float* __restrict__ gamma,
                                               const float* __restrict__ beta,
                                               float* __restrict__ sa,
                                               float* __restrict__ sb, int n) {
    int c = blockIdx.x * 256 + threadIdx.x;
    if (c < n) {
        float mean = ssum[c] * (1.f / 8192.f);
        float var = ssq[c] * (1.f / 8192.f) - mean * mean;
        float s = rsqrtf(var + 1e-5f) * gamma[c];
        sa[c] = s;
        sb[c] = beta[c] - mean * s;
    }
}

__global__ __launch_bounds__(256) void k_sig(const float* __restrict__ out_acc,
                                             const float* __restrict__ ob,
                                             float* __restrict__ out) {
    int b = blockIdx.x * 256 + threadIdx.x;
    if (b < B_SZ) {
        float v = ob[0] + out_acc[b];
        out[b] = 1.f / (1.f + expf(-v));
    }
}

extern "C" void kernel_launch(void* const* d_in, const int* in_sizes, int n_in,
                              void* d_out, int out_size, void* d_ws, size_t ws_size,
                              hipStream_t stream) {
    const float* x      = (const float*)d_in[0];
    const int*   uf     = (const int*)d_in[1];
    const float* w0     = (const float*)d_in[2];
    const float* b0     = (const float*)d_in[3];
    const float* w1     = (const float*)d_in[4];
    const float* b1     = (const float*)d_in[5];
    const float* w2     = (const float*)d_in[6];
    const float* b2     = (const float*)d_in[7];
    const float* gamma0 = (const float*)d_in[8];
    const float* beta0  = (const float*)d_in[9];
    const float* gamma1 = (const float*)d_in[10];
    const float* beta1  = (const float*)d_in[11];
    const float* ow     = (const float*)d_in[12];
    const float* ob     = (const float*)d_in[13];

    char* ws = (char*)d_ws;
    const size_t AG_BYTES = (size_t)G_SZ * B_SZ * 128 * 2;  // 209,715,200
    unsigned short* Ag = (unsigned short*)ws;
    unsigned short* h1 = Ag;  // h1 aliases Ag (Ag dead after dense0)
    float* stat = (float*)(ws + AG_BYTES);
    float* sum0    = stat;            // 10000
    float* ssq0    = stat + 10000;
    float* sum1    = stat + 20000;
    float* ssq1    = stat + 30000;
    float* out_acc = stat + 40000;    // 8192
    float* sa0     = stat + 48192;
    float* sb0     = stat + 58192;
    float* sa1     = stat + 68192;
    float* sb1     = stat + 78192;    // stats end at 88192 floats (352,768 B)

    unsigned short* p0 = (unsigned short*)(ws + AG_BYTES + 88192 * 4);
    unsigned short* p1 = p0 + (size_t)179200 * 8;   // 2,867,200 B each
    unsigned short* p2 = p1 + (size_t)179200 * 8;   // p2: 1,638,400 B

    unsigned short* h0 = (unsigned short*)((float*)d_out + B_SZ);
    float* pred = (float*)d_out + B_SZ;
    float* sig  = (float*)d_out;

    hipMemsetAsync(stat, 0, 48192 * sizeof(float), stream);

    k_packW<<<1800, 256, 0, stream>>>(w0, w1, b1, w2, b2, p0, p1, p2);
    k_gather<<<B_SZ / 16, 256, 0, stream>>>(x, uf, Ag);

    k_dense<128, 100, 7, false, false, false><<<6400, 256, 0, stream>>>(
        Ag, p0, b0, nullptr, nullptr, h0, nullptr, sum0, ssq0, nullptr, nullptr);
    k_bnfin<<<40, 256, 0, stream>>>(sum0, ssq0, gamma0, beta0, sa0, sb0, 10000);

    k_dense<100, 100, 7, true, false, true><<<6400, 256, 0, stream>>>(
        h0, p1, nullptr, sa0, sb0, h1, nullptr, sum1, ssq1, nullptr, nullptr);
    k_bnfin<<<40, 256, 0, stream>>>(sum1, ssq1, gamma1, beta1, sa1, sb1, 10000);

    k_dense<100, 50, 4, true, true, true><<<6400, 256, 0, stream>>>(
        h1, p2, nullptr, sa1, sb1, nullptr, pred, nullptr, nullptr, ow, out_acc);

    k_sig<<<32, 256, 0, stream>>>(out_acc, ob, sig);
}

// Round 7
// 429.563 us; speedup vs baseline: 2.3053x; 1.0829x over previous
//
#include <hip/hip_runtime.h>

#define B_SZ 8192
#define IN_SZ 1024
#define G_SZ 100
#define F_SZ 128

using f32x4 = __attribute__((ext_vector_type(4))) float;
using s16x8 = __attribute__((ext_vector_type(8))) short;
typedef __bf16 bf16x8 __attribute__((ext_vector_type(8)));

__device__ __forceinline__ short cvt_bf16(float f) {      // HW RNE f32->bf16
    __bf16 h = (__bf16)f;
    return __builtin_bit_cast(short, h);
}
__device__ __forceinline__ float bfs2f(short s) {
    union { unsigned u; float f; } v; v.u = ((unsigned)(unsigned short)s) << 16;
    return v.f;
}

// ---------------------------------------------------------------------------
// Gather: Ag[g][b][f] = bf16(x[b][uf[g*128+f]]).
// ---------------------------------------------------------------------------
__global__ __launch_bounds__(256) void k_gather(const float* __restrict__ x,
                                                const int* __restrict__ uf,
                                                unsigned short* __restrict__ Ag) {
    __shared__ __align__(16) unsigned short xrow[16][1032];
    const int t = threadIdx.x;
    const int b0 = blockIdx.x * 16;
    #pragma unroll
    for (int i = 0; i < 16; ++i) {
        int c4 = t + i * 256;
        int r = c4 >> 8;
        int cc = (c4 & 255) << 2;
        float4 v = *reinterpret_cast<const float4*>(&x[(size_t)(b0 + r) * IN_SZ + cc]);
        ushort4 o;
        o.x = (unsigned short)cvt_bf16(v.x); o.y = (unsigned short)cvt_bf16(v.y);
        o.z = (unsigned short)cvt_bf16(v.z); o.w = (unsigned short)cvt_bf16(v.w);
        *reinterpret_cast<ushort4*>(&xrow[r][cc]) = o;
    }
    __syncthreads();
    for (int i = 0; i < 200; ++i) {
        int c = t + i * 256;
        int ch = c & 31; int r = (c >> 5) & 15; int g = c >> 9;
        int4 id = *reinterpret_cast<const int4*>(&uf[g * F_SZ + ch * 4]);
        ushort4 o;
        o.x = xrow[r][id.x]; o.y = xrow[r][id.y]; o.z = xrow[r][id.z]; o.w = xrow[r][id.w];
        *reinterpret_cast<ushort4*>(&Ag[(((size_t)g * B_SZ + b0 + r) << 7) + ch * 4]) = o;
    }
}

// ---------------------------------------------------------------------------
// Pre-pack W (+bias at k==K_SRC when FOLD) into MFMA fragment order, K padded
// to 128: P[g][(ks*NT+nt)*64+lane] = 8 bf16 (n = nt*16+(lane&15),
//                                            k = ks*32+(lane>>4)*8 ..+7)
// ---------------------------------------------------------------------------
template<int K_SRC, int N_OUT, int NT, bool FOLD>
__device__ __forceinline__ void pack_one(int e, const float* __restrict__ W,
                                         const float* __restrict__ bias,
                                         unsigned short* __restrict__ P) {
    constexpr int EPG = 4 * NT * 64;
    int g = e / EPG; int r = e - g * EPG;
    int lane = r & 63; int nt = (r >> 6) % NT; int ks = r / (64 * NT);
    int n = nt * 16 + (lane & 15); int kb = ks * 32 + (lane >> 4) * 8;
    s16x8 v;
    #pragma unroll
    for (int j = 0; j < 8; ++j) {
        int k = kb + j; float val = 0.f;
        if (n < N_OUT) {
            if (k < K_SRC) val = W[((size_t)g * K_SRC + k) * N_OUT + n];
            else if (FOLD && k == K_SRC) val = bias[g * N_OUT + n];
        }
        v[j] = cvt_bf16(val);
    }
    *reinterpret_cast<s16x8*>(&P[(size_t)e * 8]) = v;
}

__global__ __launch_bounds__(256) void k_packW(
    const float* __restrict__ w0,
    const float* __restrict__ w1, const float* __restrict__ b1,
    const float* __restrict__ w2, const float* __restrict__ b2,
    unsigned short* __restrict__ p0, unsigned short* __restrict__ p1,
    unsigned short* __restrict__ p2) {
    int id = blockIdx.x * 256 + threadIdx.x;           // 460800 total
    if (id < 179200)       pack_one<128, 100, 7, false>(id, w0, nullptr, p0);
    else if (id < 358400)  pack_one<100, 100, 7, true >(id - 179200, w1, b1, p1);
    else                   pack_one<100,  50, 4, true >(id - 358400, w2, b2, p2);
}

// ---------------------------------------------------------------------------
// Per-group dense, bf16 MFMA 16x16x32.
//  - A fully prefetched (8 fragments) before MFMA -> max MLP per wave.
//  - W fragments per-lane from pre-packed table (L2-hot).
//  - Epilogue stores via LDS bounce (stride-136 pad, <=2-way conflicts) ->
//    fully coalesced global writes. BN stats: shfl -> LDS -> 1 atomic/chan.
//  - FRAG_IN: A is fragment-major [g][rb][ks][lane][8], K padded to 128
//    (1.0 at k=100 for bias-fold, BN identity channels >=100).
//  - FRAG_OUT: write Hout in that fragment layout (pads filled here).
//  - IS_LAST: swapped mfma(W,A) -> D[n][b]; pred bounce + out_weight dot.
//  NOTE: launch_bounds (256,4). (256,8) caps VGPR at 64 -> acc spills (R5).
// ---------------------------------------------------------------------------
template<int K_SRC, int N_OUT, int NT, bool BN_IN, bool IS_LAST, bool FRAG_IN,
         bool FRAG_OUT, bool HAS_BIAS>
__global__ __launch_bounds__(256, 4) void k_dense(
    const unsigned short* __restrict__ Ain,
    const unsigned short* __restrict__ Wf,    // [G][4*NT*64][8] packed
    const float* __restrict__ bias,           // only when HAS_BIAS
    const float* __restrict__ sa, const float* __restrict__ sb, // [G*128]
    unsigned short* __restrict__ Hout,        // row-major [g][b][100] or frag
    float* __restrict__ pred,                 // [B][5000] f32
    float* __restrict__ ssum, float* __restrict__ ssq, // [G*100]
    const float* __restrict__ ow, float* __restrict__ out_acc)
{
    constexpr int EPG = 4 * NT * 64;
    __shared__ __align__(16) unsigned short LH[IS_LAST ? 16 : 128 * 136];
    __shared__ __align__(16) float LP[IS_LAST ? 128 * 54 : 16];
    __shared__ float ls1[IS_LAST ? 1 : NT * 16];
    __shared__ float ls2[IS_LAST ? 1 : NT * 16];

    const int t = threadIdx.x;
    const int g = blockIdx.x >> 6;
    const int m0 = (blockIdx.x & 63) << 7;
    const int lane = t & 63, wid = t >> 6;
    const int lr = lane & 15, lg = lane >> 4;

    if constexpr (!IS_LAST) {
        if (t < NT * 16) { ls1[t] = 0.f; ls2[t] = 0.f; }
    }

    const unsigned short* wbase = Wf + ((size_t)g * EPG + lane) * 8;

    // ---- A prefetch: all 8 fragments issued up front ----
    s16x8 a[2][4];
    if constexpr (FRAG_IN) {
        const unsigned short* fb =
            Ain + (((size_t)(g * 512 + (m0 >> 4) + wid * 2) * 4) * 64 + lane) * 8;
        #pragma unroll
        for (int ks = 0; ks < 4; ++ks) {
            a[0][ks] = *reinterpret_cast<const s16x8*>(fb + (size_t)ks * 512);
            a[1][ks] = *reinterpret_cast<const s16x8*>(fb + (size_t)(4 + ks) * 512);
        }
    } else if constexpr (K_SRC == 128) {
        const unsigned short* r0 = Ain + ((size_t)g * B_SZ + m0 + wid * 32 + lr) * 128;
        #pragma unroll
        for (int ks = 0; ks < 4; ++ks) {
            const int kb = ks * 32 + lg * 8;
            a[0][ks] = *reinterpret_cast<const s16x8*>(r0 + kb);
            a[1][ks] = *reinterpret_cast<const s16x8*>(r0 + 16 * 128 + kb);
        }
    } else {  // K_SRC == 100, row-major
        const unsigned short* r0 = Ain + ((size_t)g * B_SZ + m0 + wid * 32 + lr) * 100;
        #pragma unroll
        for (int ks = 0; ks < 3; ++ks) {
            const int kb = ks * 32 + lg * 8;
            #pragma unroll
            for (int h = 0; h < 2; ++h) {
                reinterpret_cast<short4*>(&a[h][ks])[0] =
                    *reinterpret_cast<const short4*>(r0 + h * 16 * 100 + kb);
                reinterpret_cast<short4*>(&a[h][ks])[1] =
                    *reinterpret_cast<const short4*>(r0 + h * 16 * 100 + kb + 4);
            }
        }
        a[0][3] = s16x8{}; a[1][3] = s16x8{};
        if (lg == 0) {
            reinterpret_cast<short4*>(&a[0][3])[0] =
                *reinterpret_cast<const short4*>(r0 + 96);
            reinterpret_cast<short4*>(&a[1][3])[0] =
                *reinterpret_cast<const short4*>(r0 + 16 * 100 + 96);
        }
    }

    #define APP(vv, idx, s, o) { float f_ = bfs2f(vv[idx]) * (s) + (o); \
                                 vv[idx] = cvt_bf16(fmaxf(f_, 0.f)); }
    if constexpr (BN_IN) {
        constexpr int NB = FRAG_IN ? 4 : 3;
        #pragma unroll
        for (int ks = 0; ks < NB; ++ks) {
            const int kb = ks * 32 + lg * 8;
            float4 S0 = *reinterpret_cast<const float4*>(&sa[g * 128 + kb]);
            float4 S1 = *reinterpret_cast<const float4*>(&sa[g * 128 + kb + 4]);
            float4 O0 = *reinterpret_cast<const float4*>(&sb[g * 128 + kb]);
            float4 O1 = *reinterpret_cast<const float4*>(&sb[g * 128 + kb + 4]);
            #pragma unroll
            for (int h = 0; h < 2; ++h) {
                APP(a[h][ks],0,S0.x,O0.x) APP(a[h][ks],1,S0.y,O0.y)
                APP(a[h][ks],2,S0.z,O0.z) APP(a[h][ks],3,S0.w,O0.w)
                APP(a[h][ks],4,S1.x,O1.x) APP(a[h][ks],5,S1.y,O1.y)
                APP(a[h][ks],6,S1.z,O1.z) APP(a[h][ks],7,S1.w,O1.w)
            }
        }
        if constexpr (!FRAG_IN) {      // tail channels 96..99 + bias slot 1.0
            if (lg == 0) {
                float4 S0 = *reinterpret_cast<const float4*>(&sa[g * 128 + 96]);
                float4 O0 = *reinterpret_cast<const float4*>(&sb[g * 128 + 96]);
                #pragma unroll
                for (int h = 0; h < 2; ++h) {
                    APP(a[h][3],0,S0.x,O0.x) APP(a[h][3],1,S0.y,O0.y)
                    APP(a[h][3],2,S0.z,O0.z) APP(a[h][3],3,S0.w,O0.w)
                    a[h][3][4] = (short)0x3F80;   // 1.0 -> bias row of W
                }
            }
        }
    }
    #undef APP

    // ---- MFMA ----
    f32x4 acc[2][NT] = {};
    #pragma unroll
    for (int ks = 0; ks < 4; ++ks) {
        bf16x8 av0 = __builtin_bit_cast(bf16x8, a[0][ks]);
        bf16x8 av1 = __builtin_bit_cast(bf16x8, a[1][ks]);
        #pragma unroll
        for (int nt = 0; nt < NT; ++nt) {
            s16x8 b = *reinterpret_cast<const s16x8*>(wbase + (size_t)((ks * NT + nt) * 64) * 8);
            bf16x8 bv = __builtin_bit_cast(bf16x8, b);
            if constexpr (IS_LAST) {
                acc[0][nt] = __builtin_amdgcn_mfma_f32_16x16x32_bf16(bv, av0, acc[0][nt], 0, 0, 0);
                acc[1][nt] = __builtin_amdgcn_mfma_f32_16x16x32_bf16(bv, av1, acc[1][nt], 0, 0, 0);
            } else {
                acc[0][nt] = __builtin_amdgcn_mfma_f32_16x16x32_bf16(av0, bv, acc[0][nt], 0, 0, 0);
                acc[1][nt] = __builtin_amdgcn_mfma_f32_16x16x32_bf16(av1, bv, acc[1][nt], 0, 0, 0);
            }
        }
    }

    // ---- epilogue ----
    if constexpr (!IS_LAST) {
        __syncthreads();                       // ls init visible
        #pragma unroll
        for (int nt = 0; nt < NT; ++nt) {
            const int col = nt * 16 + lr;
            const bool valid = col < N_OUT;
            float bv = 0.f;
            if constexpr (HAS_BIAS) bv = valid ? bias[g * N_OUT + col] : 0.f;
            float s1 = 0.f, s2 = 0.f;
            #pragma unroll
            for (int mi = 0; mi < 2; ++mi) {
                const int rloc = wid * 32 + mi * 16 + (lg << 2);
                #pragma unroll
                for (int r = 0; r < 4; ++r) {
                    float v = acc[mi][nt][r] + bv;
                    short hb = cvt_bf16(v);
                    float vq = bfs2f(hb);
                    s1 += vq; s2 += vq * vq;
                    if (valid) LH[(rloc + r) * 136 + col] = (unsigned short)hb;
                }
            }
            s1 += __shfl_xor(s1, 16); s1 += __shfl_xor(s1, 32);
            s2 += __shfl_xor(s2, 16); s2 += __shfl_xor(s2, 32);
            if (valid && lg == 0) {
                atomicAdd(&ls1[col], s1);
                atomicAdd(&ls2[col], s2);
            }
        }
        if constexpr (FRAG_OUT) {              // pads: 1.0@100, zeros 101..127
            if (t < 128) {
                ushort4 v1; v1.x = 0x3F80u; v1.y = 0; v1.z = 0; v1.w = 0;
                ushort4 z;  z.x = z.y = z.z = z.w = 0;
                *reinterpret_cast<ushort4*>(&LH[t * 136 + 100]) = v1;
                #pragma unroll
                for (int j = 1; j < 7; ++j)
                    *reinterpret_cast<ushort4*>(&LH[t * 136 + 100 + j * 4]) = z;
            }
        }
        __syncthreads();
        if (t < N_OUT) {
            atomicAdd(&ssum[g * N_OUT + t], ls1[t]);
            atomicAdd(&ssq[g * N_OUT + t], ls2[t]);
        }
        if constexpr (FRAG_OUT) {
            unsigned short* hb = Hout + (((size_t)g * 512 + (m0 >> 4)) * 4 * 64) * 8;
            #pragma unroll
            for (int i = 0; i < 8; ++i) {
                int e = t + i * 256;           // e = rb*256 + ks*64 + lane
                int row = ((e >> 8) << 4) + (e & 15);
                int kb = ((e >> 6) & 3) * 32 + ((e >> 4) & 3) * 8;
                s16x8 v = *reinterpret_cast<const s16x8*>(&LH[row * 136 + kb]);
                *reinterpret_cast<s16x8*>(hb + (size_t)e * 8) = v;
            }
        } else {
            #pragma unroll
            for (int i = 0; i < 13; ++i) {
                int e = t + i * 256;
                if (e < 3200) {
                    int row = e / 25;
                    int c4 = (e - row * 25) * 4;
                    ushort4 v = *reinterpret_cast<const ushort4*>(&LH[row * 136 + c4]);
                    *reinterpret_cast<ushort4*>(
                        Hout + ((size_t)g * B_SZ + m0 + row) * 100 + c4) = v;
                }
            }
        }
    } else {
        // D[n][b]: n = nt*16+lg*4+idx, b_local = wid*32+mi*16+lr
        #pragma unroll
        for (int mi = 0; mi < 2; ++mi) {
            const int bl = wid * 32 + mi * 16 + lr;
            float dp = 0.f;
            #pragma unroll
            for (int nt = 0; nt < NT; ++nt) {
                const int n0 = nt * 16 + (lg << 2);
                f32x4 v = acc[mi][nt];
                if (nt < 3) {
                    float2 w01 = *reinterpret_cast<const float2*>(&ow[g * N_OUT + n0]);
                    float2 w23 = *reinterpret_cast<const float2*>(&ow[g * N_OUT + n0 + 2]);
                    dp += v[0] * w01.x + v[1] * w01.y + v[2] * w23.x + v[3] * w23.y;
                    LP[bl * 54 + n0 + 0] = v[0]; LP[bl * 54 + n0 + 1] = v[1];
                    LP[bl * 54 + n0 + 2] = v[2]; LP[bl * 54 + n0 + 3] = v[3];
                } else if (lg == 0) {          // n0 = 48: n=48,49 valid
                    float2 w01 = *reinterpret_cast<const float2*>(&ow[g * N_OUT + n0]);
                    dp += v[0] * w01.x + v[1] * w01.y;
                    LP[bl * 54 + n0 + 0] = v[0]; LP[bl * 54 + n0 + 1] = v[1];
                }
            }
            dp += __shfl_xor(dp, 16); dp += __shfl_xor(dp, 32);
            if (lg == 0) atomicAdd(&out_acc[m0 + bl], dp);
        }
        __syncthreads();
        #pragma unroll
        for (int i = 0; i < 13; ++i) {
            int e = t + i * 256;
            if (e < 3200) {
                int row = e / 25;
                int c2 = e - row * 25;
                float2 v = *reinterpret_cast<const float2*>(&LP[row * 54 + c2 * 2]);
                *reinterpret_cast<float2*>(
                    &pred[(size_t)(m0 + row) * 5000 + g * N_OUT + c2 * 2]) = v;
            }
        }
    }
}

// BN finalize -> per-channel scale/offset, extended to 128 ch/group with
// identity entries (for the fragment layout's pad channels).
__global__ __launch_bounds__(256) void k_bnfin(const float* __restrict__ ssum,
                                               const float* __restrict__ ssq,
                                               const float* __restrict__ gamma,
                                               const float* __restrict__ beta,
                                               float* __restrict__ sa,
                                               float* __restrict__ sb) {
    int c = blockIdx.x * 256 + threadIdx.x;
    if (c < G_SZ * 128) {
        int g = c >> 7, ch = c & 127;
        float s, o;
        if (ch < 100) {
            float mean = ssum[g * 100 + ch] * (1.f / 8192.f);
            float var = ssq[g * 100 + ch] * (1.f / 8192.f) - mean * mean;
            s = rsqrtf(var + 1e-5f) * gamma[g * 100 + ch];
            o = beta[g * 100 + ch] - mean * s;
        } else { s = 1.f; o = 0.f; }
        sa[c] = s; sb[c] = o;
    }
}

__global__ __launch_bounds__(256) void k_sig(const float* __restrict__ out_acc,
                                             const float* __restrict__ ob,
                                             float* __restrict__ out) {
    int b = blockIdx.x * 256 + threadIdx.x;
    if (b < B_SZ) {
        float v = ob[0] + out_acc[b];
        out[b] = 1.f / (1.f + expf(-v));
    }
}

extern "C" void kernel_launch(void* const* d_in, const int* in_sizes, int n_in,
                              void* d_out, int out_size, void* d_ws, size_t ws_size,
                              hipStream_t stream) {
    const float* x      = (const float*)d_in[0];
    const int*   uf     = (const int*)d_in[1];
    const float* w0     = (const float*)d_in[2];
    const float* b0     = (const float*)d_in[3];
    const float* w1     = (const float*)d_in[4];
    const float* b1     = (const float*)d_in[5];
    const float* w2     = (const float*)d_in[6];
    const float* b2     = (const float*)d_in[7];
    const float* gamma0 = (const float*)d_in[8];
    const float* beta0  = (const float*)d_in[9];
    const float* gamma1 = (const float*)d_in[10];
    const float* beta1  = (const float*)d_in[11];
    const float* ow     = (const float*)d_in[12];
    const float* ob     = (const float*)d_in[13];

    char* ws = (char*)d_ws;
    const size_t AG_BYTES = (size_t)G_SZ * B_SZ * 128 * 2;  // 209,715,200
    unsigned short* Ag  = (unsigned short*)ws;
    unsigned short* h1f = Ag;   // fragment h1 [100][512][4][64][8] = same bytes;
                                // aliases Ag (dead after dense0)
    float* stat = (float*)(ws + AG_BYTES);
    float* sum0    = stat;            // 10000
    float* ssq0    = stat + 10000;
    float* sum1    = stat + 20000;
    float* ssq1    = stat + 30000;
    float* out_acc = stat + 40000;    // 8192  (zeroed region ends at 48192)
    float* sa0     = stat + 48192;    // 12800 each, fully written by bnfin
    float* sb0     = stat + 60992;
    float* sa1     = stat + 73792;
    float* sb1     = stat + 86592;    // ends 99392 floats = 397,568 B

    unsigned short* p0 = (unsigned short*)(ws + AG_BYTES + 397568);
    unsigned short* p1 = p0 + (size_t)179200 * 8;   // 2,867,200 B each
    unsigned short* p2 = p1 + (size_t)179200 * 8;   // p2: 1,638,400 B

    // h0 row-major [100][8192][100] bf16 = 163,840,000 B, exactly the pred
    // region of d_out (dead before dense2 overwrites it with pred).
    unsigned short* h0 = (unsigned short*)((float*)d_out + B_SZ);
    float* pred = (float*)d_out + B_SZ;
    float* sig  = (float*)d_out;

    hipMemsetAsync(stat, 0, 48192 * sizeof(float), stream);

    k_packW<<<1800, 256, 0, stream>>>(w0, w1, b1, w2, b2, p0, p1, p2);
    k_gather<<<B_SZ / 16, 256, 0, stream>>>(x, uf, Ag);

    // dense0: row-major 128 in, row-major 100 out, bias in epilogue
    k_dense<128, 100, 7, false, false, false, false, true><<<6400, 256, 0, stream>>>(
        Ag, p0, b0, nullptr, nullptr, h0, nullptr, sum0, ssq0, nullptr, nullptr);
    k_bnfin<<<50, 256, 0, stream>>>(sum0, ssq0, gamma0, beta0, sa0, sb0);

    // dense1: row-major 100 in (BN+fold), fragment out
    k_dense<100, 100, 7, true, false, false, true, false><<<6400, 256, 0, stream>>>(
        h0, p1, nullptr, sa0, sb0, h1f, nullptr, sum1, ssq1, nullptr, nullptr);
    k_bnfin<<<50, 256, 0, stream>>>(sum1, ssq1, gamma1, beta1, sa1, sb1);

    // dense2: fragment in (uniform 4 ks, BN identity pads), pred + dot out
    k_dense<128, 50, 4, true, true, true, false, false><<<6400, 256, 0, stream>>>(
        h1f, p2, nullptr, sa1, sb1, nullptr, pred, nullptr, nullptr, ow, out_acc);

    k_sig<<<32, 256, 0, stream>>>(out_acc, ob, sig);
}